// Round 5
// baseline (73.573 us; speedup 1.0000x reference)
//
#include <hip/hip_runtime.h>
#include <stdint.h>

#define DI 16
#define DL 64
#define DD 1024
#define NB 32
#define PI_F 3.14159265358979323846f

#define AS1 __attribute__((address_space(1)))
#define AS3 __attribute__((address_space(3)))

// ws layout (floats): trace_partials[32][16]

// ---------------- kernel 1: trace partial for (b,c): sum_{d,p} G[c,d] * rho[b, c*64+p, d*64+p]
// G = expm(-2*lam*H_idx) computed inline (circulant closed form); 512 blocks for full-chip BW
// on the scattered 64B-line fetch (~33.5 MB irreducible).
__global__ void k_trace(const float* __restrict__ rho,
                        const float* __restrict__ t,
                        const float* __restrict__ w1,
                        const float* __restrict__ b1,
                        const float* __restrict__ w2,
                        const float* __restrict__ b2,
                        float* __restrict__ ws) {
    int c = blockIdx.x;  // 0..15
    int b = blockIdx.y;  // 0..31
    int tid = threadIdx.x; // 256 threads
    __shared__ float lam_sh;
    __shared__ float ck[16];
    __shared__ float Gs[16];
    __shared__ float part[4];

    // lambda MLP: 64 lanes, 2 TE-elements each, single-wave shuffle reduce
    if (tid < 64) {
        float tb = t[b];
        float z0 = tb * w1[tid]      + b1[tid];
        float z1 = tb * w1[tid + 64] + b1[tid + 64];
        float h0 = z0 / (1.0f + expf(-z0));
        float h1 = z1 / (1.0f + expf(-z1));
        float v = h0 * w2[tid] + h1 * w2[tid + 64];
        #pragma unroll
        for (int off = 32; off; off >>= 1) v += __shfl_down(v, off, 64);
        if (tid == 0) lam_sh = tanhf(v + b2[0]) * 0.1f;
    }
    if (tid >= 64 && tid < 80) ck[tid - 64] = cosf((PI_F / 8.0f) * (float)(tid - 64));
    __syncthreads();
    if (tid < 16) {
        float lam = lam_sh;
        int r = (c - tid) & 15;
        float sg = 0.0f;
        #pragma unroll
        for (int k = 0; k < 16; k++)
            sg += expf(-4.0f * lam * ck[k]) * ck[(k * r) & 15];
        Gs[tid] = sg * (1.0f / 16.0f);
    }
    __syncthreads();

    int p  = tid & 63;
    int dg = tid >> 6; // 0..3, each owns 4 d's
    const float* rowp = rho + (size_t)b * DD * DD + (size_t)(c * 64 + p) * DD + p;
    float s = 0.0f;
    #pragma unroll
    for (int i = 0; i < 4; i++) {
        int d = dg * 4 + i;
        s += Gs[d] * rowp[d * 64];
    }
    #pragma unroll
    for (int off = 32; off; off >>= 1) s += __shfl_down(s, off, 64);
    if ((tid & 63) == 0) part[tid >> 6] = s;
    __syncthreads();
    if (tid == 0)
        ws[b * 16 + c] = part[0] + part[1] + part[2] + part[3];
}

// ---------------- kernel 2: out[b,a,p,b',q] = inv_tr * sum_{c,d} E[a,c] E[b',d] rho[b,c,p,d,q]
// R1/R4-proven hot-loop structure, (256,2), separate T (pad 516).
// New: (a) staging via async global_load_lds width=16 (per-lane global gather,
// wave-uniform LDS dest + lane*16 — verified mapping); (b) lambda MLP + E computed
// inline (issued AFTER the async loads, so the VALU work hides under memory).
__global__ __launch_bounds__(256, 2)
void k_main(const float* __restrict__ rho,
            const float* __restrict__ t,
            const float* __restrict__ w1,
            const float* __restrict__ b1,
            const float* __restrict__ w2,
            const float* __restrict__ b2,
            const float* __restrict__ ws,
            float* __restrict__ out) {
    __shared__ float S[16 * 512];   // S[c][d][q] : c*512 + d*32 + q   (32 KB)
    __shared__ float T[16 * 516];   // T[a][d][q] : a*516 + d*32 + q   (pad 4)
    __shared__ float Es[256];
    __shared__ float ck[16];
    __shared__ float lam_sh, sinv_sh;

    int qt  = blockIdx.x;        // 0..1
    int p   = blockIdx.y;        // 0..63
    int b   = blockIdx.z;        // 0..31
    int tid = threadIdx.x;
    int q0  = qt * 32;

    // ---- (1) issue async staging: 16 c-rows x 16 d-segments x 32 floats ----
    // lane mapping: g = it*256+tid; LDS float off = (g>>7)*512 + (g&127)*4
    //             = wave-uniform base ((gw>>7)*512+(gw&127)*4) + lane*4  -> base + lane*16B
    const float* rbase = rho + (size_t)b * (DD * DD) + q0;
    #pragma unroll
    for (int it = 0; it < 8; it++) {
        int g  = it * 256 + tid;
        int c  = g >> 7;
        int r  = g & 127;
        int d  = r >> 3;
        int q4 = r & 7;
        const float* ga = rbase + (size_t)(c * 64 + p) * DD + d * 64 + q4 * 4;
        int gw = it * 256 + (tid & ~63);   // first-lane g (wave-uniform)
        unsigned fo = (unsigned)((gw >> 7) * 512 + (gw & 127) * 4);
        __builtin_amdgcn_global_load_lds((const AS1 uint32_t*)ga,
                                         (AS3 uint32_t*)&S[fo], 16, 0, 0);
    }

    // ---- (2) lambda MLP + constants (overlaps with loads in flight) ----
    if (tid < 64) {
        float tb = t[b];
        float z0 = tb * w1[tid]      + b1[tid];
        float z1 = tb * w1[tid + 64] + b1[tid + 64];
        float h0 = z0 / (1.0f + expf(-z0));
        float h1 = z1 / (1.0f + expf(-z1));
        float v = h0 * w2[tid] + h1 * w2[tid + 64];
        #pragma unroll
        for (int off = 32; off; off >>= 1) v += __shfl_down(v, off, 64);
        if (tid == 0) lam_sh = tanhf(v + b2[0]) * 0.1f;
    }
    if (tid >= 64 && tid < 80) ck[tid - 64] = cosf((PI_F / 8.0f) * (float)(tid - 64));
    if (tid == 128) {
        float tr = 0.0f;
        #pragma unroll
        for (int c = 0; c < 16; c++) tr += ws[b * 16 + c];
        sinv_sh = 1.0f / fmaxf(tr, 1e-8f);
    }
    __syncthreads();   // staging drained (vmcnt) + lam/ck visible

    // ---- (3) E = expm(-lam*H_idx), circulant closed form; one entry per thread ----
    {
        float lam = lam_sh;
        int i = tid >> 4, j = tid & 15, r = (i - j) & 15;
        float se = 0.0f;
        #pragma unroll
        for (int k = 0; k < 16; k++)
            se += expf(-2.0f * lam * ck[k]) * ck[(k * r) & 15];
        Es[tid] = se * (1.0f / 16.0f);
    }
    __syncthreads();   // Es visible

    // ---- step 1: T[a][d][q] = sum_c E[a,c] * S[c][d][q]; thread = (ah, d, q4), 8 a's each ----
    {
        int ah = tid >> 7;           // 0..1
        int d  = (tid >> 3) & 15;
        int qq = (tid & 7) * 4;
        float4 acc[8];
        #pragma unroll
        for (int i = 0; i < 8; i++) acc[i] = make_float4(0.f, 0.f, 0.f, 0.f);
        #pragma unroll
        for (int c = 0; c < 16; c++) {
            float4 s4 = *(float4*)&S[c * 512 + d * 32 + qq];
            // E symmetric: E[a][c] = Es[c*16 + a]; uniform (broadcast) reads
            float4 e0 = *(float4*)&Es[c * 16 + ah * 8];
            float4 e1 = *(float4*)&Es[c * 16 + ah * 8 + 4];
            acc[0].x += e0.x * s4.x; acc[0].y += e0.x * s4.y; acc[0].z += e0.x * s4.z; acc[0].w += e0.x * s4.w;
            acc[1].x += e0.y * s4.x; acc[1].y += e0.y * s4.y; acc[1].z += e0.y * s4.z; acc[1].w += e0.y * s4.w;
            acc[2].x += e0.z * s4.x; acc[2].y += e0.z * s4.y; acc[2].z += e0.z * s4.z; acc[2].w += e0.z * s4.w;
            acc[3].x += e0.w * s4.x; acc[3].y += e0.w * s4.y; acc[3].z += e0.w * s4.z; acc[3].w += e0.w * s4.w;
            acc[4].x += e1.x * s4.x; acc[4].y += e1.x * s4.y; acc[4].z += e1.x * s4.z; acc[4].w += e1.x * s4.w;
            acc[5].x += e1.y * s4.x; acc[5].y += e1.y * s4.y; acc[5].z += e1.y * s4.z; acc[5].w += e1.y * s4.w;
            acc[6].x += e1.z * s4.x; acc[6].y += e1.z * s4.y; acc[6].z += e1.z * s4.z; acc[6].w += e1.z * s4.w;
            acc[7].x += e1.w * s4.x; acc[7].y += e1.w * s4.y; acc[7].z += e1.w * s4.z; acc[7].w += e1.w * s4.w;
        }
        #pragma unroll
        for (int ai = 0; ai < 8; ai++)
            *(float4*)&T[(ah * 8 + ai) * 516 + d * 32 + qq] = acc[ai];
    }
    __syncthreads();

    // ---- step 2: out[a][b'][q] = sinv * sum_d E[b',d] * T[a][d][q]; thread = (ah, b', q4) ----
    {
        int ah = tid >> 7;           // 0..1
        int bp = (tid >> 3) & 15;
        int qq = (tid & 7) * 4;
        float Eb[16];
        #pragma unroll
        for (int j4 = 0; j4 < 4; j4++) {
            float4 e = *(float4*)&Es[bp * 16 + j4 * 4];
            Eb[4 * j4 + 0] = e.x; Eb[4 * j4 + 1] = e.y; Eb[4 * j4 + 2] = e.z; Eb[4 * j4 + 3] = e.w;
        }
        float sinv = sinv_sh;
        float* obase = out + (size_t)b * (DD * DD) + (size_t)p * DD + bp * 64 + q0 + qq;
        #pragma unroll
        for (int ai = 0; ai < 8; ai++) {
            int a = ah * 8 + ai;
            float4 acc = make_float4(0.f, 0.f, 0.f, 0.f);
            #pragma unroll
            for (int d = 0; d < 16; d++) {
                float4 t4 = *(float4*)&T[a * 516 + d * 32 + qq];
                acc.x += Eb[d] * t4.x; acc.y += Eb[d] * t4.y;
                acc.z += Eb[d] * t4.z; acc.w += Eb[d] * t4.w;
            }
            acc.x *= sinv; acc.y *= sinv; acc.z *= sinv; acc.w *= sinv;
            *(float4*)(obase + (size_t)a * (64 * DD)) = acc;
        }
    }
}

extern "C" void kernel_launch(void* const* d_in, const int* in_sizes, int n_in,
                              void* d_out, int out_size, void* d_ws, size_t ws_size,
                              hipStream_t stream) {
    const float* rho = (const float*)d_in[0];
    const float* t   = (const float*)d_in[1];
    const float* w1  = (const float*)d_in[2];
    const float* b1  = (const float*)d_in[3];
    const float* w2  = (const float*)d_in[4];
    const float* b2  = (const float*)d_in[5];
    // d_in[6] = H, unused: structure is fixed (16-cycle ⊗ I64), handled analytically.
    float* out = (float*)d_out;
    float* ws  = (float*)d_ws;

    k_trace<<<dim3(DI, NB), 256, 0, stream>>>(rho, t, w1, b1, w2, b2, ws);
    k_main <<<dim3(2, 64, NB), 256, 0, stream>>>(rho, t, w1, b1, w2, b2, ws, out);
}

// Round 6
// 73.360 us; speedup vs baseline: 1.0029x; 1.0029x over previous
//
#include <hip/hip_runtime.h>
#include <stdint.h>

#define DI 16
#define DL 64
#define DD 1024
#define NB 32
#define PI_F 3.14159265358979323846f

#define AS1 __attribute__((address_space(1)))
#define AS3 __attribute__((address_space(3)))

// ws layout (floats): trace_partials[32][16]

// ---------------- kernel 1: trace partial for (b,c): sum_{d,p} G[c,d] * rho[b, c*64+p, d*64+p]
// G = expm(-2*lam*H_idx) computed inline (circulant closed form); 512 blocks for full-chip BW
// on the scattered 64B-line fetch (~33.5 MB irreducible).
__global__ void k_trace(const float* __restrict__ rho,
                        const float* __restrict__ t,
                        const float* __restrict__ w1,
                        const float* __restrict__ b1,
                        const float* __restrict__ w2,
                        const float* __restrict__ b2,
                        float* __restrict__ ws) {
    int c = blockIdx.x;  // 0..15
    int b = blockIdx.y;  // 0..31
    int tid = threadIdx.x; // 256 threads
    __shared__ float lam_sh;
    __shared__ float ck[16];
    __shared__ float Gs[16];
    __shared__ float part[4];

    // lambda MLP: 64 lanes, 2 TE-elements each, single-wave shuffle reduce
    if (tid < 64) {
        float tb = t[b];
        float z0 = tb * w1[tid]      + b1[tid];
        float z1 = tb * w1[tid + 64] + b1[tid + 64];
        float h0 = z0 / (1.0f + expf(-z0));
        float h1 = z1 / (1.0f + expf(-z1));
        float v = h0 * w2[tid] + h1 * w2[tid + 64];
        #pragma unroll
        for (int off = 32; off; off >>= 1) v += __shfl_down(v, off, 64);
        if (tid == 0) lam_sh = tanhf(v + b2[0]) * 0.1f;
    }
    if (tid >= 64 && tid < 80) ck[tid - 64] = cosf((PI_F / 8.0f) * (float)(tid - 64));
    __syncthreads();
    if (tid < 16) {
        float lam = lam_sh;
        int r = (c - tid) & 15;
        float sg = 0.0f;
        #pragma unroll
        for (int k = 0; k < 16; k++)
            sg += expf(-4.0f * lam * ck[k]) * ck[(k * r) & 15];
        Gs[tid] = sg * (1.0f / 16.0f);
    }
    __syncthreads();

    int p  = tid & 63;
    int dg = tid >> 6; // 0..3, each owns 4 d's
    const float* rowp = rho + (size_t)b * DD * DD + (size_t)(c * 64 + p) * DD + p;
    float s = 0.0f;
    #pragma unroll
    for (int i = 0; i < 4; i++) {
        int d = dg * 4 + i;
        s += Gs[d] * rowp[d * 64];
    }
    #pragma unroll
    for (int off = 32; off; off >>= 1) s += __shfl_down(s, off, 64);
    if ((tid & 63) == 0) part[tid >> 6] = s;
    __syncthreads();
    if (tid == 0)
        ws[b * 16 + c] = part[0] + part[1] + part[2] + part[3];
}

// ---------------- kernel 2: out[b,a,p,b',q] = inv_tr * sum_{c,d} E[a,c] E[b',d] rho[b,c,p,d,q]
// R5 structure with ONE change: T folded into S (step-1 accumulators live in registers
// across the extra barrier) -> LDS 66 -> ~34 KB -> 4 blocks/CU if VGPR <= 128, so
// co-resident blocks' memory and compute phases overlap. launch_bounds stays (256,2)
// (VGPR cap 256 — R2 proved min-waves=4 causes spills; this cap does not).
__global__ __launch_bounds__(256, 2)
void k_main(const float* __restrict__ rho,
            const float* __restrict__ t,
            const float* __restrict__ w1,
            const float* __restrict__ b1,
            const float* __restrict__ w2,
            const float* __restrict__ b2,
            const float* __restrict__ ws,
            float* __restrict__ out) {
    __shared__ float S[16 * 512];   // S[c][d][q] : c*512 + d*32 + q (32 KB); reused as T[a][d][q]
    __shared__ float Es[256];
    __shared__ float ck[16];
    __shared__ float lam_sh, sinv_sh;

    int qt  = blockIdx.x;        // 0..1
    int p   = blockIdx.y;        // 0..63
    int b   = blockIdx.z;        // 0..31
    int tid = threadIdx.x;
    int q0  = qt * 32;

    // ---- (1) issue async staging: 16 c-rows x 16 d-segments x 32 floats ----
    // lane mapping: g = it*256+tid; LDS float off = (g>>7)*512 + (g&127)*4
    //             = wave-uniform base + lane*16B (verified R5, results bit-identical)
    const float* rbase = rho + (size_t)b * (DD * DD) + q0;
    #pragma unroll
    for (int it = 0; it < 8; it++) {
        int g  = it * 256 + tid;
        int c  = g >> 7;
        int r  = g & 127;
        int d  = r >> 3;
        int q4 = r & 7;
        const float* ga = rbase + (size_t)(c * 64 + p) * DD + d * 64 + q4 * 4;
        int gw = it * 256 + (tid & ~63);   // first-lane g (wave-uniform)
        unsigned fo = (unsigned)((gw >> 7) * 512 + (gw & 127) * 4);
        __builtin_amdgcn_global_load_lds((const AS1 uint32_t*)ga,
                                         (AS3 uint32_t*)&S[fo], 16, 0, 0);
    }

    // ---- (2) lambda MLP + constants (overlaps with loads in flight) ----
    if (tid < 64) {
        float tb = t[b];
        float z0 = tb * w1[tid]      + b1[tid];
        float z1 = tb * w1[tid + 64] + b1[tid + 64];
        float h0 = z0 / (1.0f + expf(-z0));
        float h1 = z1 / (1.0f + expf(-z1));
        float v = h0 * w2[tid] + h1 * w2[tid + 64];
        #pragma unroll
        for (int off = 32; off; off >>= 1) v += __shfl_down(v, off, 64);
        if (tid == 0) lam_sh = tanhf(v + b2[0]) * 0.1f;
    }
    if (tid >= 64 && tid < 80) ck[tid - 64] = cosf((PI_F / 8.0f) * (float)(tid - 64));
    if (tid == 128) {
        float tr = 0.0f;
        #pragma unroll
        for (int c = 0; c < 16; c++) tr += ws[b * 16 + c];
        sinv_sh = 1.0f / fmaxf(tr, 1e-8f);
    }
    __syncthreads();   // staging drained (vmcnt) + lam/ck visible

    // ---- (3) E = expm(-lam*H_idx), circulant closed form; one entry per thread ----
    {
        float lam = lam_sh;
        int i = tid >> 4, j = tid & 15, r = (i - j) & 15;
        float se = 0.0f;
        #pragma unroll
        for (int k = 0; k < 16; k++)
            se += expf(-2.0f * lam * ck[k]) * ck[(k * r) & 15];
        Es[tid] = se * (1.0f / 16.0f);
    }
    __syncthreads();   // Es visible

    // ---- step 1: T[a][d][q] = sum_c E[a,c] * S[c][d][q]; thread = (ah, d, q4), 8 a's each ----
    {
        int ah = tid >> 7;           // 0..1
        int d  = (tid >> 3) & 15;
        int qq = (tid & 7) * 4;
        float4 acc[8];
        #pragma unroll
        for (int i = 0; i < 8; i++) acc[i] = make_float4(0.f, 0.f, 0.f, 0.f);
        #pragma unroll
        for (int c = 0; c < 16; c++) {
            float4 s4 = *(float4*)&S[c * 512 + d * 32 + qq];
            // E symmetric: E[a][c] = Es[c*16 + a]; uniform (broadcast) reads
            float4 e0 = *(float4*)&Es[c * 16 + ah * 8];
            float4 e1 = *(float4*)&Es[c * 16 + ah * 8 + 4];
            acc[0].x += e0.x * s4.x; acc[0].y += e0.x * s4.y; acc[0].z += e0.x * s4.z; acc[0].w += e0.x * s4.w;
            acc[1].x += e0.y * s4.x; acc[1].y += e0.y * s4.y; acc[1].z += e0.y * s4.z; acc[1].w += e0.y * s4.w;
            acc[2].x += e0.z * s4.x; acc[2].y += e0.z * s4.y; acc[2].z += e0.z * s4.z; acc[2].w += e0.z * s4.w;
            acc[3].x += e0.w * s4.x; acc[3].y += e0.w * s4.y; acc[3].z += e0.w * s4.z; acc[3].w += e0.w * s4.w;
            acc[4].x += e1.x * s4.x; acc[4].y += e1.x * s4.y; acc[4].z += e1.x * s4.z; acc[4].w += e1.x * s4.w;
            acc[5].x += e1.y * s4.x; acc[5].y += e1.y * s4.y; acc[5].z += e1.y * s4.z; acc[5].w += e1.y * s4.w;
            acc[6].x += e1.z * s4.x; acc[6].y += e1.z * s4.y; acc[6].z += e1.z * s4.z; acc[6].w += e1.z * s4.w;
            acc[7].x += e1.w * s4.x; acc[7].y += e1.w * s4.y; acc[7].z += e1.w * s4.z; acc[7].w += e1.w * s4.w;
        }
        __syncthreads();   // all step-1 reads of S complete; safe to overwrite S with T
        #pragma unroll
        for (int ai = 0; ai < 8; ai++)
            *(float4*)&S[(ah * 8 + ai) * 512 + d * 32 + qq] = acc[ai];
    }
    __syncthreads();

    // ---- step 2: out[a][b'][q] = sinv * sum_d E[b',d] * T[a][d][q]; thread = (ah, b', q4) ----
    {
        int ah = tid >> 7;           // 0..1
        int bp = (tid >> 3) & 15;
        int qq = (tid & 7) * 4;
        float Eb[16];
        #pragma unroll
        for (int j4 = 0; j4 < 4; j4++) {
            float4 e = *(float4*)&Es[bp * 16 + j4 * 4];
            Eb[4 * j4 + 0] = e.x; Eb[4 * j4 + 1] = e.y; Eb[4 * j4 + 2] = e.z; Eb[4 * j4 + 3] = e.w;
        }
        float sinv = sinv_sh;
        float* obase = out + (size_t)b * (DD * DD) + (size_t)p * DD + bp * 64 + q0 + qq;
        #pragma unroll
        for (int ai = 0; ai < 8; ai++) {
            int a = ah * 8 + ai;
            float4 acc = make_float4(0.f, 0.f, 0.f, 0.f);
            #pragma unroll
            for (int d = 0; d < 16; d++) {
                float4 t4 = *(float4*)&S[a * 512 + d * 32 + qq];
                acc.x += Eb[d] * t4.x; acc.y += Eb[d] * t4.y;
                acc.z += Eb[d] * t4.z; acc.w += Eb[d] * t4.w;
            }
            acc.x *= sinv; acc.y *= sinv; acc.z *= sinv; acc.w *= sinv;
            *(float4*)(obase + (size_t)a * (64 * DD)) = acc;
        }
    }
}

extern "C" void kernel_launch(void* const* d_in, const int* in_sizes, int n_in,
                              void* d_out, int out_size, void* d_ws, size_t ws_size,
                              hipStream_t stream) {
    const float* rho = (const float*)d_in[0];
    const float* t   = (const float*)d_in[1];
    const float* w1  = (const float*)d_in[2];
    const float* b1  = (const float*)d_in[3];
    const float* w2  = (const float*)d_in[4];
    const float* b2  = (const float*)d_in[5];
    // d_in[6] = H, unused: structure is fixed (16-cycle ⊗ I64), handled analytically.
    float* out = (float*)d_out;
    float* ws  = (float*)d_ws;

    k_trace<<<dim3(DI, NB), 256, 0, stream>>>(rho, t, w1, b1, w2, b2, ws);
    k_main <<<dim3(2, 64, NB), 256, 0, stream>>>(rho, t, w1, b1, w2, b2, ws, out);
}